// Round 13
// baseline (464.611 us; speedup 1.0000x reference)
//
#include <hip/hip_runtime.h>
#include <hip/hip_bf16.h>

using f32x4 = __attribute__((ext_vector_type(4))) float;
using s16x8 = __attribute__((ext_vector_type(8))) short;

#define DEVFN static __device__ __forceinline__

static constexpr int NCOL = 256;
static constexpr int MROWS = 8192;
static constexpr int BM = 64;
static constexpr int BK = 32;
static constexpr int THREADS = 512;       // 8 waves: wm(2) x wn(4)
static constexpr int NTILE = MROWS / BM;  // 128
static constexpr size_t PSLICE = (size_t)MROWS * NCOL;  // shorts per partial

DEVFN unsigned short f2bf(float f) {
  union { float f; unsigned u; } x; x.f = f;
  unsigned u = x.u;
  u += 0x7fffu + ((u >> 16) & 1u);   // RNE
  return (unsigned short)(u >> 16);
}

DEVFN float bf2f(unsigned short u) {
  union { unsigned u; float f; } x; x.u = (unsigned)u << 16; return x.f;
}

DEVFN s16x8 pack8(f32x4 v0, f32x4 v1) {
  union { s16x8 v; __hip_bfloat162 h[4]; } pk;
  pk.h[0] = __float22bfloat162_rn(float2{v0[0], v0[1]});
  pk.h[1] = __float22bfloat162_rn(float2{v0[2], v0[3]});
  pk.h[2] = __float22bfloat162_rn(float2{v1[0], v1[1]});
  pk.h[3] = __float22bfloat162_rn(float2{v1[2], v1[3]});
  return pk.v;
}

DEVFN void async16(void* lds, const void* g) {
  __builtin_amdgcn_global_load_lds((const __attribute__((address_space(1))) unsigned*)g,
                                   (__attribute__((address_space(3))) unsigned*)lds,
                                   16, 0, 0);
}

// AP8-32 A-format: per 64-row x 32-k tile (row-tile T, k-tile t) a contiguous
// 4KB block at (T*KT + t)*2048 shorts, KT = K/32; within a tile element
// (row,k) at (k>>3)*512 + row*8 + (k&7).  Fragment (row, kgrp) is 16B
// contiguous; a 16-lane fragment read spans 256 contiguous bytes -> zero
// bank conflicts.  Linear global_load_lds staging order.
// B P8 format: elem(k,j) at ((k>>3)*256 + j)*8 + (k&7)  (same property).

// C[M,256] = A[M,K] @ B[K,256]; 3-deep LDS pipeline, counted per-wave vmcnt
// + raw s_barrier (ONE barrier per 32-k step, never drains mid-loop).
// Output: bf16 P8 partial slice kh (KS==1 -> directly next GEMM's B operand).
template<int KS>
__global__ __launch_bounds__(THREADS, 4)
void gemm_b(const unsigned short* __restrict__ Ap8, int Kfull,
            const unsigned short* __restrict__ Bp8,
            unsigned short* __restrict__ Pout)
{
  __shared__ __align__(16) unsigned short As[3][2048];   // 3 x 4KB
  __shared__ __align__(16) unsigned short Bs[3][8192];   // 3 x 16KB -> 60KB, 2 blk/CU

  const int nwg = NTILE * KS, q = nwg / 8;
  const int logical = (blockIdx.x & 7) * q + (blockIdx.x >> 3);  // XCD-chunked
  const int kh = logical / NTILE;
  const int tile = logical % NTILE;
  const int klen = Kfull / KS;
  const int nt = klen / BK;
  const int k0 = kh * klen;
  const int kt0 = k0 >> 5;
  const int KT = Kfull >> 5;
  const int tid = threadIdx.x, lane = tid & 63;
  const int wm = (tid >> 6) >> 2;       // 0..1 : rows wm*32..+32
  const int wn = (tid >> 6) & 3;        // 0..3 : cols wn*64..+64
  const int lr = lane & 15, lg = lane >> 4;
  const bool aw = (tid < 256);          // waves 0-3 stage A too (3 ops vs 2)

  auto stage = [&](int buf, int t) {
    if (aw)
      async16(&As[buf][tid * 8], Ap8 + ((size_t)tile * KT + kt0 + t) * 2048 + tid * 8);
    const unsigned short* bsrc = Bp8 + (size_t)(k0 + t * BK) * 256 + tid * 8;
    async16(&Bs[buf][tid * 8], bsrc);
    async16(&Bs[buf][4096 + tid * 8], bsrc + 4096);
  };

  f32x4 acc[2][4] = {};

  stage(0, 0);
  stage(1, 1);

  int cur = 0;
  for (int i = 0; i < nt; ++i) {
    // ensure MY stage(i) ops landed; allow stage(i+1)'s (3 or 2) to stay in flight
    if (i < nt - 1) {
      if (aw) asm volatile("s_waitcnt vmcnt(3)");
      else    asm volatile("s_waitcnt vmcnt(2)");
    } else {
      asm volatile("s_waitcnt vmcnt(0)");
    }
    __builtin_amdgcn_s_barrier();        // all waves' stage(i) landed; all done
                                         // reading buf[(i-1)%3]
    if (i + 2 < nt) {
      const int dst = cur ? cur - 1 : 2; // (cur+2)%3
      stage(dst, i + 2);
    }
    s16x8 a0 = *(const s16x8*)&As[cur][lg * 512 + (wm * 32 + lr) * 8];
    s16x8 a1 = *(const s16x8*)&As[cur][lg * 512 + (wm * 32 + 16 + lr) * 8];
#pragma unroll
    for (int fn = 0; fn < 4; ++fn) {
      s16x8 b = *(const s16x8*)&Bs[cur][lg * 2048 + (wn * 64 + fn * 16 + lr) * 8];
      acc[0][fn] = __builtin_amdgcn_mfma_f32_16x16x32_bf16(a0, b, acc[0][fn], 0, 0, 0);
      acc[1][fn] = __builtin_amdgcn_mfma_f32_16x16x32_bf16(a1, b, acc[1][fn], 0, 0, 0);
    }
    cur = (cur == 2) ? 0 : cur + 1;
  }

  // C/D layout: col = lane&15, row = (lane>>4)*4 + reg.  Store bf16 P8.
  unsigned short* dst = Pout + (size_t)kh * PSLICE;
#pragma unroll
  for (int fm = 0; fm < 2; ++fm) {
    const int r0 = tile * BM + wm * 32 + fm * 16 + lg * 4;   // r0&7 in {0,4}
#pragma unroll
    for (int fn = 0; fn < 4; ++fn) {
      const int col = wn * 64 + fn * 16 + lr;
      ushort4 u;
      u.x = f2bf(acc[fm][fn][0]); u.y = f2bf(acc[fm][fn][1]);
      u.z = f2bf(acc[fm][fn][2]); u.w = f2bf(acc[fm][fn][3]);
      *(ushort4*)&dst[((size_t)(r0 >> 3) * 256 + col) * 8 + (r0 & 7)] = u;
    }
  }
}

// ---- stream conversion kernels (memcpy-class) ---------------------------

// f32 row-major [M][K] -> AP8-32 bf16. One thread per 8 elements (row, k8).
// KTSH = log2(K/32). Reads 128B contiguous per 4 lanes; writes 4x256B chunks
// per wave -> both coalesced.
template<int KTSH>
__global__ void k_cvt_ap8(const float* __restrict__ W, unsigned short* __restrict__ outp) {
  const int K = 32 << KTSH;
  size_t gid = (size_t)blockIdx.x * blockDim.x + threadIdx.x;
  const int k8 = (int)(gid & 3);
  const size_t rr = gid >> 2;
  const int row = (int)(rr & 63);
  const size_t bt = rr >> 6;                 // T*KT + t
  const int t = (int)(bt & ((1 << KTSH) - 1));
  const size_t T = bt >> KTSH;
  const float* p = W + (T * 64 + row) * (size_t)K + t * 32 + k8 * 8;
  s16x8 v = pack8(*(const f32x4*)p, *(const f32x4*)(p + 4));
  *(s16x8*)&outp[bt * 2048 + k8 * 512 + row * 8] = v;
}

// f32 [K][256] -> P8 bf16 (weights)
__global__ void k_convert_p8(const float* __restrict__ W, int K,
                             unsigned short* __restrict__ outp) {
  int tid = blockIdx.x * blockDim.x + threadIdx.x;
  if (tid >= K * NCOL / 4) return;
  int j = tid & (NCOL - 1);
  int i0 = (tid >> 8) << 2;
  unsigned short u[4];
#pragma unroll
  for (int r = 0; r < 4; ++r) u[r] = f2bf(W[(size_t)(i0 + r) * NCOL + j]);
  size_t off = ((size_t)(i0 >> 3) * NCOL + j) * 8 + (i0 & 7);
  *(ushort4*)&outp[off] = make_ushort4(u[0], u[1], u[2], u[3]);
}

// sum 4 bf16-P8 partials. One thread per (8-row group, col).
// MODE 0: P8 bf16 out (optional per-row filt); MODE 1: relu -> AP8-32 bf16
// (K=256, KT=8); MODE 2: f32 row-major out.
template<int MODE>
__global__ void k_reduce(const unsigned short* __restrict__ P,
                         const float* __restrict__ filt, void* __restrict__ Out) {
  const int tid = blockIdx.x * blockDim.x + threadIdx.x;   // 262144 threads
  const int j = tid & 255;
  const int i8 = tid >> 8;
  const int i0 = i8 * 8;
  const size_t base = ((size_t)i8 * 256 + j) * 8;
  s16x8 p0 = *(const s16x8*)&P[base];
  s16x8 p1 = *(const s16x8*)&P[base + PSLICE];
  s16x8 p2 = *(const s16x8*)&P[base + 2 * PSLICE];
  s16x8 p3 = *(const s16x8*)&P[base + 3 * PSLICE];
  float f[8];
#pragma unroll
  for (int r = 0; r < 8; ++r)
    f[r] = bf2f((unsigned short)p0[r]) + bf2f((unsigned short)p1[r])
         + bf2f((unsigned short)p2[r]) + bf2f((unsigned short)p3[r]);
  if constexpr (MODE == 0) {
    if (filt) {
#pragma unroll
      for (int r = 0; r < 8; ++r) f[r] *= filt[i0 + r];
    }
    union { s16x8 v; unsigned short u[8]; } o;
#pragma unroll
    for (int r = 0; r < 8; ++r) o.u[r] = f2bf(f[r]);
    *(s16x8*)&((unsigned short*)Out)[base] = o.v;
  } else if constexpr (MODE == 1) {
    unsigned short* O = (unsigned short*)Out;
#pragma unroll
    for (int r = 0; r < 8; ++r) {
      const int row = i0 + r;
      // AP8-32, K=256 (KT=8): tile (row>>6, j>>5)
      O[((size_t)(row >> 6) * 8 + (j >> 5)) * 2048 + ((j >> 3) & 3) * 512
        + (row & 63) * 8 + (j & 7)] = f2bf(fmaxf(f[r], 0.f));
    }
  } else {
    float* O = (float*)Out;
#pragma unroll
    for (int r = 0; r < 8; ++r)
      O[(size_t)(i0 + r) * NCOL + j] = f[r];
  }
}

extern "C" void kernel_launch(void* const* d_in, const int* in_sizes, int n_in,
                              void* d_out, int out_size, void* d_ws, size_t ws_size,
                              hipStream_t stream) {
  const float* input = (const float*)d_in[0];
  const float* Wv    = (const float*)d_in[1];
  const float* Winv  = (const float*)d_in[2];
  const float* W1    = (const float*)d_in[3];
  const float* W2    = (const float*)d_in[4];
  const float* f1    = (const float*)d_in[5];
  const float* f2    = (const float*)d_in[6];
  float* out = (float*)d_out;

  char* ws = (char*)d_ws;
  unsigned short* WvB   = (unsigned short*)(ws);                 // 128MB AP8
  unsigned short* WinvB = (unsigned short*)(ws + 0x8000000);     // 128MB AP8
  unsigned short* inB   = (unsigned short*)(ws + 0x10000000);    // 8MB AP8
  unsigned short* partB = (unsigned short*)(ws + 0x10800000);    // 16MB (4 x bf16 P8)
  unsigned short* t1p   = (unsigned short*)(ws + 0x11800000);    // 4MB each, P8
  unsigned short* s1p   = (unsigned short*)(ws + 0x11C00000);
  unsigned short* t2p   = (unsigned short*)(ws + 0x12000000);
  unsigned short* s2p   = (unsigned short*)(ws + 0x12400000);
  unsigned short* h1b   = (unsigned short*)(ws + 0x12800000);    // 4MB AP8
  unsigned short* W1p   = (unsigned short*)(ws + 0x12C00000);    // 256KB
  unsigned short* W2p   = (unsigned short*)(ws + 0x12C40000);    // 128KB

  dim3 gT(THREADS);
  dim3 g4(NTILE * 4), g1(NTILE);                       // 512 / 128 WGs
  dim3 rT(256), rG(MROWS * NCOL / 8 / 256);            // 1024 WGs

  // stream converts (memcpy-class)
  k_cvt_ap8<8><<<dim3(32768), rT, 0, stream>>>(Wv, WvB);
  k_cvt_ap8<8><<<dim3(32768), rT, 0, stream>>>(Winv, WinvB);
  k_cvt_ap8<4><<<dim3(2048),  rT, 0, stream>>>(input, inB);
  k_convert_p8<<<dim3(128), rT, 0, stream>>>(W1, 512, W1p);
  k_convert_p8<<<dim3(64),  rT, 0, stream>>>(W2, 256, W2p);

  // t1 = input @ W1                  (K=512, KS=1 -> direct P8)
  gemm_b<1><<<g1, gT, 0, stream>>>(inB, 512, W1p, t1p);
  // s1 = diag(f1).(Winv @ t1)
  gemm_b<4><<<g4, gT, 0, stream>>>(WinvB, 8192, t1p, partB);
  k_reduce<0><<<rG, rT, 0, stream>>>(partB, f1, s1p);
  // h1 = relu(Wv @ s1) -> AP8
  gemm_b<4><<<g4, gT, 0, stream>>>(WvB, 8192, s1p, partB);
  k_reduce<1><<<rG, rT, 0, stream>>>(partB, nullptr, h1b);
  // t2 = h1 @ W2                     (K=256, KS=1 -> direct P8)
  gemm_b<1><<<g1, gT, 0, stream>>>(h1b, 256, W2p, t2p);
  // s2 = diag(f2).(Winv @ t2)
  gemm_b<4><<<g4, gT, 0, stream>>>(WinvB, 8192, t2p, partB);
  k_reduce<0><<<rG, rT, 0, stream>>>(partB, f2, s2p);
  // out = Wv @ s2
  gemm_b<4><<<g4, gT, 0, stream>>>(WvB, 8192, s2p, partB);
  k_reduce<2><<<rG, rT, 0, stream>>>(partB, nullptr, out);
}

// Round 14
// 386.574 us; speedup vs baseline: 1.2019x; 1.2019x over previous
//
#include <hip/hip_runtime.h>
#include <hip/hip_bf16.h>

using f32x4 = __attribute__((ext_vector_type(4))) float;
using s16x8 = __attribute__((ext_vector_type(8))) short;

#define DEVFN static __device__ __forceinline__

static constexpr int NCOL = 256;
static constexpr int MROWS = 8192;
static constexpr int BM = 64;
static constexpr int BK = 64;
static constexpr int THREADS = 512;       // 8 waves: wm(2) x wn(4)
static constexpr int NTILE = MROWS / BM;  // 128
static constexpr size_t PSLICE = (size_t)MROWS * NCOL;  // shorts per partial

DEVFN unsigned short f2bf(float f) {
  union { float f; unsigned u; } x; x.f = f;
  unsigned u = x.u;
  u += 0x7fffu + ((u >> 16) & 1u);   // RNE
  return (unsigned short)(u >> 16);
}

DEVFN float bf2f(unsigned short u) {
  union { unsigned u; float f; } x; x.u = (unsigned)u << 16; return x.f;
}

DEVFN s16x8 pack8(f32x4 v0, f32x4 v1) {
  union { s16x8 v; __hip_bfloat162 h[4]; } pk;
  pk.h[0] = __float22bfloat162_rn(float2{v0[0], v0[1]});
  pk.h[1] = __float22bfloat162_rn(float2{v0[2], v0[3]});
  pk.h[2] = __float22bfloat162_rn(float2{v1[0], v1[1]});
  pk.h[3] = __float22bfloat162_rn(float2{v1[2], v1[3]});
  return pk.v;
}

DEVFN void async16(void* lds, const void* g) {
  __builtin_amdgcn_global_load_lds((const __attribute__((address_space(1))) unsigned*)g,
                                   (__attribute__((address_space(3))) unsigned*)lds,
                                   16, 0, 0);
}

// ABLK bf16 A-format: per 64x64 tile (row-tile T, k-tile t) a contiguous 8KB
// block at (T*KT + t)*4096 shorts; within, element (row,k) at
// row*64 + (((k>>3) ^ (row&7))<<3) + (k&7). Linear global_load_lds order with
// the XOR bank-swizzle pre-baked into the global layout.

// C[M,256] = A[M,K] @ B[K,256]; A ABLK bf16, B P8 bf16
// (elem(k,j) at ((k>>3)*256+j)*8+(k&7)).
// R11 skeleton + T4 counted-vmcnt: stage(t+1) stays in flight across the
// barrier (vmcnt(5)); two raw s_barriers per iter, NO mid-loop vmcnt(0).
// Output: bf16 P8 partial slice kh (KS==1: kh=0 -> next GEMM's B operand).
template<int KS>
__global__ __launch_bounds__(THREADS, 4)
void gemm_b(const unsigned short* __restrict__ Ablk, int Kfull,
            const unsigned short* __restrict__ Bp8,
            unsigned short* __restrict__ Pout)
{
  __shared__ __align__(16) unsigned short As[2][BM * BK];     // 2 x 8KB
  __shared__ __align__(16) unsigned short Bs[2][BK * NCOL];   // 2 x 32KB

  const int nwg = NTILE * KS, q = nwg / 8;
  const int logical = (blockIdx.x & 7) * q + (blockIdx.x >> 3);  // XCD-chunked
  const int kh = logical / NTILE;
  const int tile = logical % NTILE;
  const int klen = Kfull / KS;
  const int nt = klen / BK;
  const int k0 = kh * klen;
  const int KT = Kfull >> 6;
  const int tid = threadIdx.x, lane = tid & 63;
  const int wm = (tid >> 6) >> 2;       // 0..1 : rows wm*32..+32
  const int wn = (tid >> 6) & 3;        // 0..3 : cols wn*64..+64
  const int lr = lane & 15, lg = lane >> 4;

  auto stage = [&](int buf, int t) {    // 5 async ops / thread, all linear
    const unsigned short* asrc = Ablk + ((size_t)tile * KT + (k0 >> 6) + t) * 4096 + tid * 8;
    async16(&As[buf][tid * 8], asrc);
    const unsigned short* bsrc = Bp8 + (size_t)(k0 + t * BK) * NCOL + tid * 8;
#pragma unroll
    for (int o = 0; o < 4; ++o)
      async16(&Bs[buf][o * 4096 + tid * 8], bsrc + o * 4096);
  };

  f32x4 acc[2][4] = {};

  stage(0, 0);

  int cur = 0;
  for (int t = 0; t < nt; ++t) {
    if (t + 1 < nt) {
      stage(cur ^ 1, t + 1);                 // prefetch stays in flight
      asm volatile("s_waitcnt vmcnt(5)");    // stage(t) landed (own 5 ops)
    } else {
      asm volatile("s_waitcnt vmcnt(0)");    // tail: drain
    }
    __builtin_amdgcn_s_barrier();            // all waves' stage(t) landed
    __builtin_amdgcn_sched_barrier(0);       // pin LDS reads below barrier
#pragma unroll
    for (int s = 0; s < 2; ++s) {
      const int kc = s * 4 + lg;        // 0..7
      const int r0 = wm * 32 + lr, r1 = r0 + 16;
      s16x8 a0 = *(const s16x8*)&As[cur][r0 * 64 + ((kc ^ (r0 & 7)) << 3)];
      s16x8 a1 = *(const s16x8*)&As[cur][r1 * 64 + ((kc ^ (r1 & 7)) << 3)];
#pragma unroll
      for (int fn = 0; fn < 4; ++fn) {
        s16x8 b = *(const s16x8*)&Bs[cur][kc * 2048 + (wn * 64 + fn * 16 + lr) * 8];
        acc[0][fn] = __builtin_amdgcn_mfma_f32_16x16x32_bf16(a0, b, acc[0][fn], 0, 0, 0);
        acc[1][fn] = __builtin_amdgcn_mfma_f32_16x16x32_bf16(a1, b, acc[1][fn], 0, 0, 0);
      }
    }
    __builtin_amdgcn_s_barrier();            // all waves done reading buf cur
    cur ^= 1;
  }

  // C/D layout: col = lane&15, row = (lane>>4)*4 + reg.  Store bf16 P8.
  unsigned short* dst = Pout + (size_t)kh * PSLICE;
#pragma unroll
  for (int fm = 0; fm < 2; ++fm) {
    const int r0 = tile * BM + wm * 32 + fm * 16 + lg * 4;   // r0&7 in {0,4}
#pragma unroll
    for (int fn = 0; fn < 4; ++fn) {
      const int col = wn * 64 + fn * 16 + lr;
      ushort4 u;
      u.x = f2bf(acc[fm][fn][0]); u.y = f2bf(acc[fm][fn][1]);
      u.z = f2bf(acc[fm][fn][2]); u.w = f2bf(acc[fm][fn][3]);
      *(ushort4*)&dst[((size_t)(r0 >> 3) * 256 + col) * 8 + (r0 & 7)] = u;
    }
  }
}

// ---- stream conversion kernels (memcpy-class) ---------------------------

// f32 row-major [M][K] -> ABLK bf16. One thread per 8 elements. KTSH=log2(K/64).
template<int KTSH>
__global__ void k_cvt_ablk(const float* __restrict__ W, unsigned short* __restrict__ outp) {
  const int K = 64 << KTSH;
  size_t gid = (size_t)blockIdx.x * blockDim.x + threadIdx.x;
  const int k8 = (int)(gid & 7);
  const size_t rr = gid >> 3;
  const int row = (int)(rr & 63);
  const size_t bt = rr >> 6;                 // T*KT + t
  const int t = (int)(bt & ((1 << KTSH) - 1));
  const size_t T = bt >> KTSH;
  const float* p = W + (T * 64 + row) * (size_t)K + t * 64 + k8 * 8;
  s16x8 v = pack8(*(const f32x4*)p, *(const f32x4*)(p + 4));
  *(s16x8*)&outp[bt * 4096 + row * 64 + ((k8 ^ (row & 7)) << 3)] = v;
}

// f32 [K][256] -> P8 bf16 (weights)
__global__ void k_convert_p8(const float* __restrict__ W, int K,
                             unsigned short* __restrict__ outp) {
  int tid = blockIdx.x * blockDim.x + threadIdx.x;
  if (tid >= K * NCOL / 4) return;
  int j = tid & (NCOL - 1);
  int i0 = (tid >> 8) << 2;
  unsigned short u[4];
#pragma unroll
  for (int r = 0; r < 4; ++r) u[r] = f2bf(W[(size_t)(i0 + r) * NCOL + j]);
  size_t off = ((size_t)(i0 >> 3) * NCOL + j) * 8 + (i0 & 7);
  *(ushort4*)&outp[off] = make_ushort4(u[0], u[1], u[2], u[3]);
}

// sum 4 bf16-P8 partials. One thread per (8-row group, col).
// MODE 0: P8 bf16 out (optional per-row filt); MODE 1: relu -> ABLK bf16
// (K=256, KT=4); MODE 2: f32 row-major out.
template<int MODE>
__global__ void k_reduce(const unsigned short* __restrict__ P,
                         const float* __restrict__ filt, void* __restrict__ Out) {
  const int tid = blockIdx.x * blockDim.x + threadIdx.x;   // 262144 threads
  const int j = tid & 255;
  const int i8 = tid >> 8;
  const int i0 = i8 * 8;
  const size_t base = ((size_t)i8 * 256 + j) * 8;
  s16x8 p0 = *(const s16x8*)&P[base];
  s16x8 p1 = *(const s16x8*)&P[base + PSLICE];
  s16x8 p2 = *(const s16x8*)&P[base + 2 * PSLICE];
  s16x8 p3 = *(const s16x8*)&P[base + 3 * PSLICE];
  float f[8];
#pragma unroll
  for (int r = 0; r < 8; ++r)
    f[r] = bf2f((unsigned short)p0[r]) + bf2f((unsigned short)p1[r])
         + bf2f((unsigned short)p2[r]) + bf2f((unsigned short)p3[r]);
  if constexpr (MODE == 0) {
    if (filt) {
#pragma unroll
      for (int r = 0; r < 8; ++r) f[r] *= filt[i0 + r];
    }
    union { s16x8 v; unsigned short u[8]; } o;
#pragma unroll
    for (int r = 0; r < 8; ++r) o.u[r] = f2bf(f[r]);
    *(s16x8*)&((unsigned short*)Out)[base] = o.v;
  } else if constexpr (MODE == 1) {
    unsigned short* O = (unsigned short*)Out;
#pragma unroll
    for (int r = 0; r < 8; ++r) {
      const int row = i0 + r;
      O[((size_t)(row >> 6) * 4 + (j >> 6)) * 4096 + (row & 63) * 64
        + ((((j >> 3) & 7) ^ (row & 7)) << 3) + (j & 7)] = f2bf(fmaxf(f[r], 0.f));
    }
  } else {
    float* O = (float*)Out;
#pragma unroll
    for (int r = 0; r < 8; ++r)
      O[(size_t)(i0 + r) * NCOL + j] = f[r];
  }
}

extern "C" void kernel_launch(void* const* d_in, const int* in_sizes, int n_in,
                              void* d_out, int out_size, void* d_ws, size_t ws_size,
                              hipStream_t stream) {
  const float* input = (const float*)d_in[0];
  const float* Wv    = (const float*)d_in[1];
  const float* Winv  = (const float*)d_in[2];
  const float* W1    = (const float*)d_in[3];
  const float* W2    = (const float*)d_in[4];
  const float* f1    = (const float*)d_in[5];
  const float* f2    = (const float*)d_in[6];
  float* out = (float*)d_out;

  char* ws = (char*)d_ws;
  unsigned short* WvB   = (unsigned short*)(ws);                 // 128MB ABLK
  unsigned short* WinvB = (unsigned short*)(ws + 0x8000000);     // 128MB ABLK
  unsigned short* inB   = (unsigned short*)(ws + 0x10000000);    // 8MB ABLK
  unsigned short* partB = (unsigned short*)(ws + 0x10800000);    // 16MB (4 x bf16 P8)
  unsigned short* t1p   = (unsigned short*)(ws + 0x11800000);    // 4MB each, P8
  unsigned short* s1p   = (unsigned short*)(ws + 0x11C00000);
  unsigned short* t2p   = (unsigned short*)(ws + 0x12000000);
  unsigned short* s2p   = (unsigned short*)(ws + 0x12400000);
  unsigned short* h1b   = (unsigned short*)(ws + 0x12800000);    // 4MB ABLK
  unsigned short* W1p   = (unsigned short*)(ws + 0x12C00000);    // 256KB
  unsigned short* W2p   = (unsigned short*)(ws + 0x12C40000);    // 128KB

  dim3 gT(THREADS);
  dim3 g4(NTILE * 4), g1(NTILE);                       // 512 / 128 WGs
  dim3 rT(256), rG(MROWS * NCOL / 8 / 256);            // 1024 WGs

  // stream converts (memcpy-class)
  k_cvt_ablk<7><<<dim3(32768), rT, 0, stream>>>(Wv, WvB);
  k_cvt_ablk<7><<<dim3(32768), rT, 0, stream>>>(Winv, WinvB);
  k_cvt_ablk<3><<<dim3(2048),  rT, 0, stream>>>(input, inB);
  k_convert_p8<<<dim3(128), rT, 0, stream>>>(W1, 512, W1p);
  k_convert_p8<<<dim3(64),  rT, 0, stream>>>(W2, 256, W2p);

  // t1 = input @ W1                  (K=512, KS=1 -> direct P8)
  gemm_b<1><<<g1, gT, 0, stream>>>(inB, 512, W1p, t1p);
  // s1 = diag(f1).(Winv @ t1)
  gemm_b<4><<<g4, gT, 0, stream>>>(WinvB, 8192, t1p, partB);
  k_reduce<0><<<rG, rT, 0, stream>>>(partB, f1, s1p);
  // h1 = relu(Wv @ s1) -> ABLK
  gemm_b<4><<<g4, gT, 0, stream>>>(WvB, 8192, s1p, partB);
  k_reduce<1><<<rG, rT, 0, stream>>>(partB, nullptr, h1b);
  // t2 = h1 @ W2                     (K=256, KS=1 -> direct P8)
  gemm_b<1><<<g1, gT, 0, stream>>>(h1b, 256, W2p, t2p);
  // s2 = diag(f2).(Winv @ t2)
  gemm_b<4><<<g4, gT, 0, stream>>>(WinvB, 8192, t2p, partB);
  k_reduce<0><<<rG, rT, 0, stream>>>(partB, f2, s2p);
  // out = Wv @ s2
  gemm_b<4><<<g4, gT, 0, stream>>>(WvB, 8192, s2p, partB);
  k_reduce<2><<<rG, rT, 0, stream>>>(partB, nullptr, out);
}